// Round 3
// baseline (420.806 us; speedup 1.0000x reference)
//
#include <hip/hip_runtime.h>
#include <hip/hip_bf16.h>

#define NT 64
#define DIM 128

typedef __attribute__((ext_vector_type(8))) short short8;
typedef __attribute__((ext_vector_type(4))) short short4v;
typedef __attribute__((ext_vector_type(8))) __bf16 bf16x8;
typedef __attribute__((ext_vector_type(4))) float floatx4;

#define MFMA(a,b,c) __builtin_amdgcn_mfma_f32_16x16x32_bf16(a,b,c,0,0,0)
// XOR-swizzle on short-index: byte bits 4-6 = short bits 3-5, bijective per row
#define SWZ(idx, row) ((idx) ^ (((row)&7)<<3))

__device__ __forceinline__ short bfbits(float f) {
  return __builtin_bit_cast(short, (__bf16)f);
}

// 8 consecutive f32 from global -> bf16 fragment
__device__ __forceinline__ bf16x8 gfrag_f32(const float* __restrict__ p) {
  float4 a = *(const float4*)p;
  float4 b = *(const float4*)(p + 4);
  bf16x8 v;
  v[0]=(__bf16)a.x; v[1]=(__bf16)a.y; v[2]=(__bf16)a.z; v[3]=(__bf16)a.w;
  v[4]=(__bf16)b.x; v[5]=(__bf16)b.y; v[6]=(__bf16)b.z; v[7]=(__bf16)b.w;
  return v;
}

// 8 bf16 (16B) from global ws or LDS
__device__ __forceinline__ bf16x8 frag_bf(const short* __restrict__ p) {
  return __builtin_bit_cast(bf16x8, *(const short8*)p);
}

// ---------------- prep: CPB MLP + bias packing + weight bf16 pack ----------
// block 0: bias_packed[f], f = (((h*4+mt)*4+nt)*64+lane)*4+i  (MFMA C order)
// blocks 1..16: convert [q_w | kv_w | proj_w] (65536 f32) -> bf16
__global__ void prep_kernel(const float* __restrict__ table,
                            const float* __restrict__ w1,
                            const float* __restrict__ b1,
                            const float* __restrict__ w2,
                            const int*   __restrict__ idx,
                            const float* __restrict__ q_w,
                            const float* __restrict__ kv_w,
                            const float* __restrict__ proj_w,
                            float* __restrict__ bias_packed,
                            short* __restrict__ wbf) {
  int t = threadIdx.x;
  if (blockIdx.x == 0) {
    __shared__ float logits[225][4];
    if (t < 225) {
      float t0 = table[2*t], t1 = table[2*t+1];
      float a0=0.f, a1=0.f, a2=0.f, a3=0.f;
      for (int j = 0; j < 512; ++j) {
        float h = fmaxf(0.f, t0 * w1[2*j] + t1 * w1[2*j+1] + b1[j]);
        a0 += h * w2[j];
        a1 += h * w2[512 + j];
        a2 += h * w2[1024 + j];
        a3 += h * w2[1536 + j];
      }
      logits[t][0]=a0; logits[t][1]=a1; logits[t][2]=a2; logits[t][3]=a3;
    }
    __syncthreads();
    for (int f = t; f < 16384; f += 256) {
      int i    = f & 3;
      int lane = (f >> 2) & 63;
      int nt   = (f >> 8) & 3;
      int mt   = (f >> 10) & 3;
      int h    = (f >> 12) & 3;
      int r = mt*16 + (lane >> 4)*4 + i;
      int c = nt*16 + (lane & 15);
      int p = idx[r*64 + c];
      float v = logits[p][h];
      bias_packed[f] = 16.f / (1.f + __expf(-v));
    }
  } else {
    int gidx = (blockIdx.x - 1) * 4096 + t * 16;
    const float* src; int off;
    if (gidx < 16384)      { src = q_w;    off = gidx; }
    else if (gidx < 49152) { src = kv_w;   off = gidx - 16384; }
    else                   { src = proj_w; off = gidx - 49152; }
    const float4* s = (const float4*)(src + off);
    short* dst = wbf + gidx;
#pragma unroll
    for (int i = 0; i < 2; ++i) {
      float4 a = s[2*i], b = s[2*i+1];
      short8 v;
      v[0]=bfbits(a.x); v[1]=bfbits(a.y); v[2]=bfbits(a.z); v[3]=bfbits(a.w);
      v[4]=bfbits(b.x); v[5]=bfbits(b.y); v[6]=bfbits(b.z); v[7]=bfbits(b.w);
      *(short8*)(dst + i*8) = v;
    }
  }
}

// ---------------- main fused kernel: one block (512 thr) per window --------
// wave = (head h, row-half s). No x/ctx staging: A-fragments load directly
// from global (L2-hot within block). LDS 48KB -> 3 blocks/CU.
__global__ __launch_bounds__(512, 6)
void swin_ctx_attn_kernel(const float* __restrict__ x, const float* __restrict__ ctx,
                          const float* __restrict__ mask,
                          const short* __restrict__ wq, const float* __restrict__ q_b,
                          const short* __restrict__ wkv, const float* __restrict__ v_b,
                          const float* __restrict__ logit_scale,
                          const short* __restrict__ wproj, const float* __restrict__ proj_b,
                          const float* __restrict__ bias_p,
                          float* __restrict__ out) {
  __shared__ short lds[24576] __attribute__((aligned(16)));  // 48 KB
  const int tid  = threadIdx.x;
  const int lane = tid & 63;
  const int wv   = tid >> 6;      // 0..7
  const int h    = wv >> 1;       // head
  const int s    = wv & 1;        // row-half
  const int b    = blockIdx.x;
  const int lr   = lane & 15;
  const int lg   = lane >> 4;

  short* qn     = lds + h*6144;   // [64][32] swz
  short* kn     = qn + 2048;      // [64][32] swz
  short* vT     = qn + 4096;      // [32][64] swz (row = channel d)
  short* attnb  = qn;             // [64][64] swz, overlays qn+kn
  short* outp_l = lds;            // [64][128] swz, overlays head0 + head1-qn

  const float* xw = x   + (size_t)b*(NT*DIM);
  const float* cw = ctx + (size_t)b*(NT*DIM);

  // ---- Q = x @ q_w.T + q_b ; l2norm ; -> qn (own 32 rows) ----
  {
    floatx4 acc[2][2] = {};
    for (int ks = 0; ks < 4; ++ks) {
      bf16x8 A[2], B[2];
#pragma unroll
      for (int m = 0; m < 2; ++m)
        A[m] = gfrag_f32(xw + (s*32 + m*16 + lr)*DIM + ks*32 + lg*8);
#pragma unroll
      for (int n = 0; n < 2; ++n)
        B[n] = frag_bf(wq + (h*32 + n*16 + lr)*DIM + ks*32 + lg*8);
#pragma unroll
      for (int n = 0; n < 2; ++n)
#pragma unroll
        for (int m = 0; m < 2; ++m)
          acc[m][n] = MFMA(A[m], B[n], acc[m][n]);
    }
    float qb0 = q_b[h*32 + lr], qb1 = q_b[h*32 + 16 + lr];
#pragma unroll
    for (int m = 0; m < 2; ++m) {
      floatx4 ss;
#pragma unroll
      for (int i = 0; i < 4; ++i) {
        acc[m][0][i] += qb0; acc[m][1][i] += qb1;
        ss[i] = acc[m][0][i]*acc[m][0][i] + acc[m][1][i]*acc[m][1][i];
      }
      for (int mm = 1; mm < 16; mm <<= 1)
#pragma unroll
        for (int i = 0; i < 4; ++i) ss[i] += __shfl_xor(ss[i], mm, 64);
#pragma unroll
      for (int i = 0; i < 4; ++i) {
        float sc = 1.0f / fmaxf(sqrtf(ss[i]), 1e-12f);
        int row = s*32 + m*16 + lg*4 + i;
        qn[SWZ(row*32 + lr,      row)] = bfbits(acc[m][0][i] * sc);
        qn[SWZ(row*32 + 16 + lr, row)] = bfbits(acc[m][1][i] * sc);
      }
    }
  }

  // ---- K,V = ctx @ kv_w.T (shared A-frags) ; K: l2norm -> kn ; V: +v_b -> vT
  {
    floatx4 kacc[2][2] = {}, vacc[2][2] = {};
    for (int ks = 0; ks < 4; ++ks) {
      bf16x8 A[2], Bk[2], Bv[2];
#pragma unroll
      for (int m = 0; m < 2; ++m)
        A[m] = gfrag_f32(cw + (s*32 + m*16 + lr)*DIM + ks*32 + lg*8);
#pragma unroll
      for (int n = 0; n < 2; ++n) {
        Bk[n] = frag_bf(wkv + (h*32 + n*16 + lr)*DIM + ks*32 + lg*8);
        Bv[n] = frag_bf(wkv + (DIM + h*32 + n*16 + lr)*DIM + ks*32 + lg*8);
      }
#pragma unroll
      for (int n = 0; n < 2; ++n)
#pragma unroll
        for (int m = 0; m < 2; ++m) {
          kacc[m][n] = MFMA(A[m], Bk[n], kacc[m][n]);
          vacc[m][n] = MFMA(A[m], Bv[n], vacc[m][n]);
        }
    }
#pragma unroll
    for (int m = 0; m < 2; ++m) {
      floatx4 ss;
#pragma unroll
      for (int i = 0; i < 4; ++i)
        ss[i] = kacc[m][0][i]*kacc[m][0][i] + kacc[m][1][i]*kacc[m][1][i];
      for (int mm = 1; mm < 16; mm <<= 1)
#pragma unroll
        for (int i = 0; i < 4; ++i) ss[i] += __shfl_xor(ss[i], mm, 64);
#pragma unroll
      for (int i = 0; i < 4; ++i) {
        float sc = 1.0f / fmaxf(sqrtf(ss[i]), 1e-12f);
        int row = s*32 + m*16 + lg*4 + i;
        kn[SWZ(row*32 + lr,      row)] = bfbits(kacc[m][0][i] * sc);
        kn[SWZ(row*32 + 16 + lr, row)] = bfbits(kacc[m][1][i] * sc);
      }
    }
    float vb0 = v_b[h*32 + lr], vb1 = v_b[h*32 + 16 + lr];
#pragma unroll
    for (int m = 0; m < 2; ++m)
#pragma unroll
      for (int n = 0; n < 2; ++n) {
        float vb = n ? vb1 : vb0;
        short4v s4;
#pragma unroll
        for (int i = 0; i < 4; ++i) s4[i] = bfbits(vacc[m][n][i] + vb);
        int d = n*16 + lr, tok0 = s*32 + m*16 + lg*4;
        *(short4v*)(vT + SWZ(d*64 + tok0, d)) = s4;
      }
  }
  __syncthreads();  // B1: qn/kn/vT ready

  // ---- S = qn @ kn^T (own 32 rows x 64, K=32) ----
  floatx4 sacc[2][4] = {};
  {
    bf16x8 A[2], Bf[4];
#pragma unroll
    for (int m = 0; m < 2; ++m) {
      int q = s*32 + m*16 + lr;
      A[m] = frag_bf(qn + SWZ(q*32 + lg*8, q));
    }
#pragma unroll
    for (int n = 0; n < 4; ++n) {
      int r = n*16 + lr;
      Bf[n] = frag_bf(kn + SWZ(r*32 + lg*8, r));
    }
#pragma unroll
    for (int n = 0; n < 4; ++n)
#pragma unroll
      for (int m = 0; m < 2; ++m)
        sacc[m][n] = MFMA(A[m], Bf[n], sacc[m][n]);
  }

  // ---- scale, +bias, +mask, softmax (own rows) ----
  {
    float scl = __expf(fminf(logit_scale[h], 4.605170185988091f));  // log(100)
    int wimg = b & 63;
#pragma unroll
    for (int m = 0; m < 2; ++m)
#pragma unroll
      for (int nt = 0; nt < 4; ++nt) {
        floatx4 bias4 = ((const floatx4*)bias_p)[(h*16 + (s*2+m)*4 + nt)*64 + lane];
#pragma unroll
        for (int i = 0; i < 4; ++i) {
          int r = s*32 + m*16 + lg*4 + i, c = nt*16 + lr;
          sacc[m][nt][i] = sacc[m][nt][i]*scl + bias4[i] + mask[((size_t)wimg*64 + r)*64 + c];
        }
      }
#pragma unroll
    for (int m = 0; m < 2; ++m) {
      floatx4 rmax;
#pragma unroll
      for (int i = 0; i < 4; ++i)
        rmax[i] = fmaxf(fmaxf(sacc[m][0][i], sacc[m][1][i]), fmaxf(sacc[m][2][i], sacc[m][3][i]));
      for (int mm = 1; mm < 16; mm <<= 1)
#pragma unroll
        for (int i = 0; i < 4; ++i) rmax[i] = fmaxf(rmax[i], __shfl_xor(rmax[i], mm, 64));
      floatx4 rsum = {};
#pragma unroll
      for (int nt = 0; nt < 4; ++nt)
#pragma unroll
        for (int i = 0; i < 4; ++i) {
          sacc[m][nt][i] = __expf(sacc[m][nt][i] - rmax[i]);
          rsum[i] += sacc[m][nt][i];
        }
      for (int mm = 1; mm < 16; mm <<= 1)
#pragma unroll
        for (int i = 0; i < 4; ++i) rsum[i] += __shfl_xor(rsum[i], mm, 64);
#pragma unroll
      for (int i = 0; i < 4; ++i) rsum[i] = 1.0f / rsum[i];
#pragma unroll
      for (int nt = 0; nt < 4; ++nt)
#pragma unroll
        for (int i = 0; i < 4; ++i) sacc[m][nt][i] *= rsum[i];
    }
  }
  __syncthreads();  // B2: all qn/kn reads done; attnb may overwrite

  // ---- P (bf16) -> attnb (own rows) ----
#pragma unroll
  for (int m = 0; m < 2; ++m)
#pragma unroll
    for (int nt = 0; nt < 4; ++nt)
#pragma unroll
      for (int i = 0; i < 4; ++i) {
        int q = s*32 + m*16 + lg*4 + i;
        attnb[SWZ(q*64 + nt*16 + lr, q)] = bfbits(sacc[m][nt][i]);
      }
  asm volatile("s_waitcnt lgkmcnt(0)" ::: "memory");
  __builtin_amdgcn_sched_barrier(0);

  // ---- O = P @ V (own 32 rows x 32 ch, K=64) ----
  floatx4 oacc[2][2] = {};
#pragma unroll
  for (int ks = 0; ks < 2; ++ks) {
    bf16x8 A[2], Bf[2];
#pragma unroll
    for (int m = 0; m < 2; ++m) {
      int q = s*32 + m*16 + lr;
      A[m] = frag_bf(attnb + SWZ(q*64 + ks*32 + lg*8, q));
    }
#pragma unroll
    for (int n = 0; n < 2; ++n) {
      int d = n*16 + lr;
      Bf[n] = frag_bf(vT + SWZ(d*64 + ks*32 + lg*8, d));
    }
#pragma unroll
    for (int n = 0; n < 2; ++n)
#pragma unroll
      for (int m = 0; m < 2; ++m)
        oacc[m][n] = MFMA(A[m], Bf[n], oacc[m][n]);
  }
  __syncthreads();  // B3: PV done everywhere; out_pre may overwrite

  // ---- out_pre (bf16) -> outp_l ----
#pragma unroll
  for (int m = 0; m < 2; ++m)
#pragma unroll
    for (int n = 0; n < 2; ++n)
#pragma unroll
      for (int i = 0; i < 4; ++i) {
        int q = s*32 + m*16 + lg*4 + i;
        outp_l[SWZ(q*128 + h*32 + n*16 + lr, q)] = bfbits(oacc[m][n][i]);
      }
  __syncthreads();  // B4: out_pre ready

  // ---- out = out_pre @ proj_w.T + proj_b ----
  {
    floatx4 acc[2][2] = {};
    for (int ks = 0; ks < 4; ++ks) {
      bf16x8 A[2], B[2];
#pragma unroll
      for (int m = 0; m < 2; ++m) {
        int q = s*32 + m*16 + lr;
        A[m] = frag_bf(outp_l + SWZ(q*128 + ks*32 + lg*8, q));
      }
#pragma unroll
      for (int n = 0; n < 2; ++n)
        B[n] = frag_bf(wproj + (h*32 + n*16 + lr)*DIM + ks*32 + lg*8);
#pragma unroll
      for (int n = 0; n < 2; ++n)
#pragma unroll
        for (int m = 0; m < 2; ++m)
          acc[m][n] = MFMA(A[m], B[n], acc[m][n]);
    }
    float pb0 = proj_b[h*32 + lr], pb1 = proj_b[h*32 + 16 + lr];
    float* outp = out + (size_t)b * (NT*DIM);
#pragma unroll
    for (int m = 0; m < 2; ++m)
#pragma unroll
      for (int n = 0; n < 2; ++n) {
        float pb = n ? pb1 : pb0;
#pragma unroll
        for (int i = 0; i < 4; ++i)
          outp[(s*32 + m*16 + lg*4 + i)*DIM + h*32 + n*16 + lr] = acc[m][n][i] + pb;
      }
  }
}

extern "C" void kernel_launch(void* const* d_in, const int* in_sizes, int n_in,
                              void* d_out, int out_size, void* d_ws, size_t ws_size,
                              hipStream_t stream) {
  const float* x     = (const float*)d_in[0];
  const float* ctx   = (const float*)d_in[1];
  const float* mask  = (const float*)d_in[2];
  const float* q_w   = (const float*)d_in[3];
  const float* q_b   = (const float*)d_in[4];
  const float* kv_w  = (const float*)d_in[5];
  const float* v_b   = (const float*)d_in[6];
  const float* ls    = (const float*)d_in[7];
  const float* w1    = (const float*)d_in[8];
  const float* b1    = (const float*)d_in[9];
  const float* w2    = (const float*)d_in[10];
  const float* pw    = (const float*)d_in[11];
  const float* pb    = (const float*)d_in[12];
  const float* table = (const float*)d_in[13];
  const int*   idx   = (const int*)d_in[14];

  float* bias_p = (float*)d_ws;                       // 16384 f32 = 64 KB
  short* wbf    = (short*)((char*)d_ws + 65536);      // 65536 bf16 = 128 KB
  short* wq     = wbf;
  short* wkv    = wbf + 16384;
  short* wproj  = wbf + 49152;
  int B = in_sizes[0] / (NT * DIM);

  prep_kernel<<<17, 256, 0, stream>>>(table, w1, b1, w2, idx, q_w, kv_w, pw,
                                      bias_p, wbf);
  swin_ctx_attn_kernel<<<B, 512, 0, stream>>>(x, ctx, mask, wq, q_b, wkv, v_b,
                                              ls, wproj, pb, bias_p, (float*)d_out);
}

// Round 4
// 267.304 us; speedup vs baseline: 1.5743x; 1.5743x over previous
//
#include <hip/hip_runtime.h>
#include <hip/hip_bf16.h>

#define NT 64
#define DIM 128

typedef __attribute__((ext_vector_type(8))) short short8;
typedef __attribute__((ext_vector_type(4))) short short4v;
typedef __attribute__((ext_vector_type(8))) __bf16 bf16x8;
typedef __attribute__((ext_vector_type(4))) float floatx4;

#define MFMA(a,b,c) __builtin_amdgcn_mfma_f32_16x16x32_bf16(a,b,c,0,0,0)
// flat-index XOR swizzle (bijective; keeps 16B granules): byte bits 4-6 ^= row bits
#define SWZ(idx, row) ((idx) ^ (((row)&7)<<3))

__device__ __forceinline__ short bfbits(float f) {
  return __builtin_bit_cast(short, (__bf16)f);
}

__device__ __forceinline__ bf16x8 frag_bf(const short* __restrict__ p) {
  return __builtin_bit_cast(bf16x8, *(const short8*)p);
}

__device__ __forceinline__ short8 pack8(float4 a, float4 b) {
  short8 v;
  v[0]=bfbits(a.x); v[1]=bfbits(a.y); v[2]=bfbits(a.z); v[3]=bfbits(a.w);
  v[4]=bfbits(b.x); v[5]=bfbits(b.y); v[6]=bfbits(b.z); v[7]=bfbits(b.w);
  return v;
}

// ---------------- prep: CPB MLP + bias packing + weight bf16 pack ----------
__global__ void prep_kernel(const float* __restrict__ table,
                            const float* __restrict__ w1,
                            const float* __restrict__ b1,
                            const float* __restrict__ w2,
                            const int*   __restrict__ idx,
                            const float* __restrict__ q_w,
                            const float* __restrict__ kv_w,
                            const float* __restrict__ proj_w,
                            float* __restrict__ bias_packed,
                            short* __restrict__ wbf) {
  int t = threadIdx.x;
  if (blockIdx.x == 0) {
    __shared__ float logits[225][4];
    if (t < 225) {
      float t0 = table[2*t], t1 = table[2*t+1];
      float a0=0.f, a1=0.f, a2=0.f, a3=0.f;
      for (int j = 0; j < 512; ++j) {
        float h = fmaxf(0.f, t0 * w1[2*j] + t1 * w1[2*j+1] + b1[j]);
        a0 += h * w2[j];
        a1 += h * w2[512 + j];
        a2 += h * w2[1024 + j];
        a3 += h * w2[1536 + j];
      }
      logits[t][0]=a0; logits[t][1]=a1; logits[t][2]=a2; logits[t][3]=a3;
    }
    __syncthreads();
    for (int f = t; f < 16384; f += 256) {
      int i    = f & 3;
      int lane = (f >> 2) & 63;
      int nt   = (f >> 8) & 3;
      int mt   = (f >> 10) & 3;
      int h    = (f >> 12) & 3;
      int r = mt*16 + (lane >> 4)*4 + i;
      int c = nt*16 + (lane & 15);
      int p = idx[r*64 + c];
      float v = logits[p][h];
      bias_packed[f] = 16.f / (1.f + __expf(-v));
    }
  } else {
    int gidx = (blockIdx.x - 1) * 4096 + t * 16;
    const float* src; int off;
    if (gidx < 16384)      { src = q_w;    off = gidx; }
    else if (gidx < 49152) { src = kv_w;   off = gidx - 16384; }
    else                   { src = proj_w; off = gidx - 49152; }
    const float4* s = (const float4*)(src + off);
    short* dst = wbf + gidx;
#pragma unroll
    for (int i = 0; i < 2; ++i)
      *(short8*)(dst + i*8) = pack8(s[2*i], s[2*i+1]);
  }
}

// ---------------- main fused kernel: one block (512 thr) per window --------
// wave = (head h, row-half s). x+ctx staged together pre-B1; 4 barriers total.
__global__ __launch_bounds__(512, 4)
void swin_ctx_attn_kernel(const float* __restrict__ x, const float* __restrict__ ctx,
                          const float* __restrict__ mask,
                          const short* __restrict__ wq, const float* __restrict__ q_b,
                          const short* __restrict__ wkv, const float* __restrict__ v_b,
                          const float* __restrict__ logit_scale,
                          const short* __restrict__ wproj, const float* __restrict__ proj_b,
                          const float* __restrict__ bias_p,
                          float* __restrict__ out) {
  __shared__ short lds[40960] __attribute__((aligned(16)));  // 80 KB -> 2 blk/CU
  const int tid  = threadIdx.x;
  const int lane = tid & 63;
  const int wv   = tid >> 6;      // 0..7
  const int h    = wv >> 1;       // head
  const int s    = wv & 1;        // row-half
  const int b    = blockIdx.x;
  const int lr   = lane & 15;
  const int lg   = lane >> 4;

  short* sx     = lds;              // [64][128] swz : x, later out_pre
  short* scx    = lds + 8192;       // [64][128] swz : ctx
  short* qn     = lds + 16384 + h*6144;  // [64][32] swz
  short* kn     = qn + 2048;        // [64][32] swz
  short* vT     = qn + 4096;        // [32][64] swz (row = channel)
  short* attnb  = qn;               // [64][64] swz, overlays qn+kn
  short* outp_l = sx;               // overlays x stage

  const float* xw = x   + (size_t)b*(NT*DIM);
  const float* cw = ctx + (size_t)b*(NT*DIM);

  // ---- stage x AND ctx together (all loads in flight at once) ----
  {
    const int sr = tid >> 3, sc0 = (tid & 7) * 16;
    const float4* xs = (const float4*)(xw + sr*DIM + sc0);
    const float4* cs = (const float4*)(cw + sr*DIM + sc0);
    float4 xr[4], cr[4];
#pragma unroll
    for (int i = 0; i < 4; ++i) xr[i] = xs[i];
#pragma unroll
    for (int i = 0; i < 4; ++i) cr[i] = cs[i];
#pragma unroll
    for (int i = 0; i < 2; ++i)
      *(short8*)(sx + SWZ(sr*128 + sc0 + i*8, sr)) = pack8(xr[2*i], xr[2*i+1]);
#pragma unroll
    for (int i = 0; i < 2; ++i)
      *(short8*)(scx + SWZ(sr*128 + sc0 + i*8, sr)) = pack8(cr[2*i], cr[2*i+1]);
  }
  // prefetch Q weights (independent of staging; overlaps barrier)
  bf16x8 Bq[4][2];
#pragma unroll
  for (int ks = 0; ks < 4; ++ks)
#pragma unroll
    for (int n = 0; n < 2; ++n)
      Bq[ks][n] = frag_bf(wq + (h*32 + n*16 + lr)*DIM + ks*32 + lg*8);
  __syncthreads();  // B1: x + ctx staged

  // ---- Q = x @ q_w.T + q_b ; l2norm ; -> qn (own 32 rows) ----
  {
    floatx4 acc[2][2] = {};
    for (int ks = 0; ks < 4; ++ks) {
      bf16x8 A[2];
#pragma unroll
      for (int m = 0; m < 2; ++m) {
        int q = s*32 + m*16 + lr;
        A[m] = frag_bf(sx + SWZ(q*128 + ks*32 + lg*8, q));
      }
#pragma unroll
      for (int n = 0; n < 2; ++n)
#pragma unroll
        for (int m = 0; m < 2; ++m)
          acc[m][n] = MFMA(A[m], Bq[ks][n], acc[m][n]);
    }
    float qb0 = q_b[h*32 + lr], qb1 = q_b[h*32 + 16 + lr];
#pragma unroll
    for (int m = 0; m < 2; ++m) {
      floatx4 ss;
#pragma unroll
      for (int i = 0; i < 4; ++i) {
        acc[m][0][i] += qb0; acc[m][1][i] += qb1;
        ss[i] = acc[m][0][i]*acc[m][0][i] + acc[m][1][i]*acc[m][1][i];
      }
      for (int mm = 1; mm < 16; mm <<= 1)
#pragma unroll
        for (int i = 0; i < 4; ++i) ss[i] += __shfl_xor(ss[i], mm, 64);
#pragma unroll
      for (int i = 0; i < 4; ++i) {
        float sc = 1.0f / fmaxf(sqrtf(ss[i]), 1e-12f);
        int row = s*32 + m*16 + lg*4 + i;
        qn[SWZ(row*32 + lr,      row)] = bfbits(acc[m][0][i] * sc);
        qn[SWZ(row*32 + 16 + lr, row)] = bfbits(acc[m][1][i] * sc);
      }
    }
  }

  // ---- K,V = ctx @ kv_w.T (shared A-frags) ----
  {
    floatx4 kacc[2][2] = {}, vacc[2][2] = {};
    for (int ks = 0; ks < 4; ++ks) {
      bf16x8 A[2], Bk[2], Bv[2];
#pragma unroll
      for (int m = 0; m < 2; ++m) {
        int q = s*32 + m*16 + lr;
        A[m] = frag_bf(scx + SWZ(q*128 + ks*32 + lg*8, q));
      }
#pragma unroll
      for (int n = 0; n < 2; ++n) {
        Bk[n] = frag_bf(wkv + (h*32 + n*16 + lr)*DIM + ks*32 + lg*8);
        Bv[n] = frag_bf(wkv + (DIM + h*32 + n*16 + lr)*DIM + ks*32 + lg*8);
      }
#pragma unroll
      for (int n = 0; n < 2; ++n)
#pragma unroll
        for (int m = 0; m < 2; ++m) {
          kacc[m][n] = MFMA(A[m], Bk[n], kacc[m][n]);
          vacc[m][n] = MFMA(A[m], Bv[n], vacc[m][n]);
        }
    }
#pragma unroll
    for (int m = 0; m < 2; ++m) {
      floatx4 ss;
#pragma unroll
      for (int i = 0; i < 4; ++i)
        ss[i] = kacc[m][0][i]*kacc[m][0][i] + kacc[m][1][i]*kacc[m][1][i];
      for (int mm = 1; mm < 16; mm <<= 1)
#pragma unroll
        for (int i = 0; i < 4; ++i) ss[i] += __shfl_xor(ss[i], mm, 64);
#pragma unroll
      for (int i = 0; i < 4; ++i) {
        float sc = 1.0f / fmaxf(sqrtf(ss[i]), 1e-12f);
        int row = s*32 + m*16 + lg*4 + i;
        kn[SWZ(row*32 + lr,      row)] = bfbits(kacc[m][0][i] * sc);
        kn[SWZ(row*32 + 16 + lr, row)] = bfbits(kacc[m][1][i] * sc);
      }
    }
    float vb0 = v_b[h*32 + lr], vb1 = v_b[h*32 + 16 + lr];
#pragma unroll
    for (int m = 0; m < 2; ++m)
#pragma unroll
      for (int n = 0; n < 2; ++n) {
        float vb = n ? vb1 : vb0;
        short4v s4;
#pragma unroll
        for (int i = 0; i < 4; ++i) s4[i] = bfbits(vacc[m][n][i] + vb);
        int d = n*16 + lr, tok0 = s*32 + m*16 + lg*4;
        *(short4v*)(vT + SWZ(d*64 + tok0, d)) = s4;
      }
  }
  __syncthreads();  // B2: qn/kn/vT ready; sx/scx reads done

  // ---- S = qn @ kn^T (own 32 rows x 64, K=32) ----
  floatx4 sacc[2][4] = {};
  {
    bf16x8 A[2], Bf[4];
#pragma unroll
    for (int m = 0; m < 2; ++m) {
      int q = s*32 + m*16 + lr;
      A[m] = frag_bf(qn + SWZ(q*32 + lg*8, q));
    }
#pragma unroll
    for (int n = 0; n < 4; ++n) {
      int r = n*16 + lr;
      Bf[n] = frag_bf(kn + SWZ(r*32 + lg*8, r));
    }
#pragma unroll
    for (int n = 0; n < 4; ++n)
#pragma unroll
      for (int m = 0; m < 2; ++m)
        sacc[m][n] = MFMA(A[m], Bf[n], sacc[m][n]);
  }

  // ---- scale, +bias, +mask, softmax (registers only) ----
  {
    float scl = __expf(fminf(logit_scale[h], 4.605170185988091f));  // log(100)
    int wimg = b & 63;
#pragma unroll
    for (int m = 0; m < 2; ++m)
#pragma unroll
      for (int nt = 0; nt < 4; ++nt) {
        floatx4 bias4 = ((const floatx4*)bias_p)[(h*16 + (s*2+m)*4 + nt)*64 + lane];
#pragma unroll
        for (int i = 0; i < 4; ++i) {
          int r = s*32 + m*16 + lg*4 + i, c = nt*16 + lr;
          sacc[m][nt][i] = sacc[m][nt][i]*scl + bias4[i] + mask[((size_t)wimg*64 + r)*64 + c];
        }
      }
#pragma unroll
    for (int m = 0; m < 2; ++m) {
      floatx4 rmax;
#pragma unroll
      for (int i = 0; i < 4; ++i)
        rmax[i] = fmaxf(fmaxf(sacc[m][0][i], sacc[m][1][i]), fmaxf(sacc[m][2][i], sacc[m][3][i]));
      for (int mm = 1; mm < 16; mm <<= 1)
#pragma unroll
        for (int i = 0; i < 4; ++i) rmax[i] = fmaxf(rmax[i], __shfl_xor(rmax[i], mm, 64));
      floatx4 rsum = {};
#pragma unroll
      for (int nt = 0; nt < 4; ++nt)
#pragma unroll
        for (int i = 0; i < 4; ++i) {
          sacc[m][nt][i] = __expf(sacc[m][nt][i] - rmax[i]);
          rsum[i] += sacc[m][nt][i];
        }
      for (int mm = 1; mm < 16; mm <<= 1)
#pragma unroll
        for (int i = 0; i < 4; ++i) rsum[i] += __shfl_xor(rsum[i], mm, 64);
#pragma unroll
      for (int i = 0; i < 4; ++i) rsum[i] = 1.0f / rsum[i];
#pragma unroll
      for (int nt = 0; nt < 4; ++nt)
#pragma unroll
        for (int i = 0; i < 4; ++i) sacc[m][nt][i] *= rsum[i];
    }
  }
  __syncthreads();  // B3: all qn/kn ds_reads done -> attnb overlay safe

  // ---- P (bf16) -> attnb (own rows) ----
#pragma unroll
  for (int m = 0; m < 2; ++m)
#pragma unroll
    for (int nt = 0; nt < 4; ++nt)
#pragma unroll
      for (int i = 0; i < 4; ++i) {
        int q = s*32 + m*16 + lg*4 + i;
        attnb[SWZ(q*64 + nt*16 + lr, q)] = bfbits(sacc[m][nt][i]);
      }
  asm volatile("s_waitcnt lgkmcnt(0)" ::: "memory");
  __builtin_amdgcn_sched_barrier(0);

  // ---- O = P @ V (own 32 rows x 32 ch, K=64) ----
  floatx4 oacc[2][2] = {};
#pragma unroll
  for (int ks = 0; ks < 2; ++ks) {
    bf16x8 A[2], Bf[2];
#pragma unroll
    for (int m = 0; m < 2; ++m) {
      int q = s*32 + m*16 + lr;
      A[m] = frag_bf(attnb + SWZ(q*64 + ks*32 + lg*8, q));
    }
#pragma unroll
    for (int n = 0; n < 2; ++n) {
      int d = n*16 + lr;
      Bf[n] = frag_bf(vT + SWZ(d*64 + ks*32 + lg*8, d));
    }
#pragma unroll
    for (int n = 0; n < 2; ++n)
#pragma unroll
      for (int m = 0; m < 2; ++m)
        oacc[m][n] = MFMA(A[m], Bf[n], oacc[m][n]);
  }

  // ---- out_pre (bf16) -> outp_l (sx region; dead since B2) ----
#pragma unroll
  for (int m = 0; m < 2; ++m)
#pragma unroll
    for (int n = 0; n < 2; ++n)
#pragma unroll
      for (int i = 0; i < 4; ++i) {
        int q = s*32 + m*16 + lg*4 + i;
        outp_l[SWZ(q*128 + h*32 + n*16 + lr, q)] = bfbits(oacc[m][n][i]);
      }
  __syncthreads();  // B4: out_pre ready

  // ---- out = out_pre @ proj_w.T + proj_b ----
  {
    floatx4 acc[2][2] = {};
    for (int ks = 0; ks < 4; ++ks) {
      bf16x8 A[2], B[2];
#pragma unroll
      for (int m = 0; m < 2; ++m) {
        int q = s*32 + m*16 + lr;
        A[m] = frag_bf(outp_l + SWZ(q*128 + ks*32 + lg*8, q));
      }
#pragma unroll
      for (int n = 0; n < 2; ++n)
        B[n] = frag_bf(wproj + (h*32 + n*16 + lr)*DIM + ks*32 + lg*8);
#pragma unroll
      for (int n = 0; n < 2; ++n)
#pragma unroll
        for (int m = 0; m < 2; ++m)
          acc[m][n] = MFMA(A[m], B[n], acc[m][n]);
    }
    float pb0 = proj_b[h*32 + lr], pb1 = proj_b[h*32 + 16 + lr];
    float* outp = out + (size_t)b * (NT*DIM);
#pragma unroll
    for (int m = 0; m < 2; ++m)
#pragma unroll
      for (int n = 0; n < 2; ++n) {
        float pb = n ? pb1 : pb0;
#pragma unroll
        for (int i = 0; i < 4; ++i)
          outp[(s*32 + m*16 + lg*4 + i)*DIM + h*32 + n*16 + lr] = acc[m][n][i] + pb;
      }
  }
}

extern "C" void kernel_launch(void* const* d_in, const int* in_sizes, int n_in,
                              void* d_out, int out_size, void* d_ws, size_t ws_size,
                              hipStream_t stream) {
  const float* x     = (const float*)d_in[0];
  const float* ctx   = (const float*)d_in[1];
  const float* mask  = (const float*)d_in[2];
  const float* q_w   = (const float*)d_in[3];
  const float* q_b   = (const float*)d_in[4];
  const float* kv_w  = (const float*)d_in[5];
  const float* v_b   = (const float*)d_in[6];
  const float* ls    = (const float*)d_in[7];
  const float* w1    = (const float*)d_in[8];
  const float* b1    = (const float*)d_in[9];
  const float* w2    = (const float*)d_in[10];
  const float* pw    = (const float*)d_in[11];
  const float* pb    = (const float*)d_in[12];
  const float* table = (const float*)d_in[13];
  const int*   idx   = (const int*)d_in[14];

  float* bias_p = (float*)d_ws;                       // 16384 f32 = 64 KB
  short* wbf    = (short*)((char*)d_ws + 65536);      // 65536 bf16 = 128 KB
  short* wq     = wbf;
  short* wkv    = wbf + 16384;
  short* wproj  = wbf + 49152;
  int B = in_sizes[0] / (NT * DIM);

  prep_kernel<<<17, 256, 0, stream>>>(table, w1, b1, w2, idx, q_w, kv_w, pw,
                                      bias_p, wbf);
  swin_ctx_attn_kernel<<<B, 512, 0, stream>>>(x, ctx, mask, wq, q_b, wkv, v_b,
                                              ls, wproj, pb, bias_p, (float*)d_out);
}